// Round 1
// baseline (1404.122 us; speedup 1.0000x reference)
//
#include <hip/hip_runtime.h>
#include <math.h>

#define HDIM 70
#define HPAD 72
#define GATES 280
#define TLEN 512
#define BATCH 128
#define CDIM 1104
#define ROWS 65536  // BATCH*TLEN

// ws layout (float offsets)
#define OFF_WRN    0
#define OFF_E      77312
#define OFF_HOUT   (77312 + 4718592)
#define OFF_ENERGY (77312 + 2*4718592)

// ---------------- K1: row renorm of embed_w ----------------
__global__ __launch_bounds__(64) void k_renorm(const float* __restrict__ w,
                                               float* __restrict__ wrn) {
    const int row = blockIdx.x;
    const int lane = threadIdx.x;
    const float* wr = w + row * HDIM;
    float v0 = wr[lane];                       // lanes 0..63
    float v1 = (lane < 6) ? wr[64 + lane] : 0.0f;
    float ss = v0 * v0 + v1 * v1;
    #pragma unroll
    for (int off = 32; off > 0; off >>= 1) ss += __shfl_down(ss, off);
    float tot = __shfl(ss, 0);
    float n = sqrtf(tot);
    float scale = (n > 1.0f) ? 1.0f / (n + 1e-7f) : 1.0f;
    wrn[row * HDIM + lane] = v0 * scale;
    if (lane < 6) wrn[row * HDIM + 64 + lane] = v1 * scale;
}

// ---------------- K2: e = x @ wrn  (M=65536,K=1104,N=70) ----------------
// 72 rows/block, thread = (rg 0..17)x(hg 0..13): 4 rows x 5 cols micro-tile.
#define KC 92
#define RTILE 72
__global__ __launch_bounds__(256) void k_embed_gemm(const float* __restrict__ x,
                                                    const float* __restrict__ wrn,
                                                    float* __restrict__ e) {
    __shared__ __align__(16) float xT[KC][76];    // transposed x chunk [c][r]
    __shared__ __align__(16) float wL[KC * HDIM]; // w chunk [c][h]
    const int tid = threadIdx.x;
    const int rbase = blockIdx.x * RTILE;
    const int hg = tid % 14;
    const int rg = tid / 14;          // 0..17 active (252 threads)
    const int h0 = hg * 5;
    float acc[4][5];
    #pragma unroll
    for (int j = 0; j < 4; ++j)
        #pragma unroll
        for (int k = 0; k < 5; ++k) acc[j][k] = 0.0f;

    for (int kc = 0; kc < 12; ++kc) {
        // stage x chunk (72 rows x 92 cols), transposed into LDS
        for (int i = tid; i < RTILE * 23; i += 256) {
            int r = i / 23, cf = i % 23;
            int gr = rbase + r;
            float4 v = make_float4(0.f, 0.f, 0.f, 0.f);
            if (gr < ROWS)
                v = *(const float4*)(x + (size_t)gr * CDIM + kc * KC + cf * 4);
            int c = cf * 4;
            xT[c][r] = v.x; xT[c + 1][r] = v.y; xT[c + 2][r] = v.z; xT[c + 3][r] = v.w;
        }
        // stage w chunk (92x70 floats = 1610 float4, contiguous)
        {
            const float4* src = (const float4*)(wrn + kc * KC * HDIM);
            float4* dst = (float4*)wL;
            for (int i = tid; i < 1610; i += 256) dst[i] = src[i];
        }
        __syncthreads();
        if (rg < 18) {
            #pragma unroll 2
            for (int c = 0; c < KC; ++c) {
                float4 xv = *(const float4*)&xT[c][rg * 4];
                const float* wp = &wL[c * HDIM + h0];
                float wv[5];
                #pragma unroll
                for (int k = 0; k < 5; ++k) wv[k] = wp[k];
                float xa[4] = {xv.x, xv.y, xv.z, xv.w};
                #pragma unroll
                for (int j = 0; j < 4; ++j)
                    #pragma unroll
                    for (int k = 0; k < 5; ++k) acc[j][k] += xa[j] * wv[k];
            }
        }
        __syncthreads();
    }
    if (rg < 18) {
        #pragma unroll
        for (int j = 0; j < 4; ++j) {
            int r = rbase + rg * 4 + j;
            if (r < ROWS) {
                float* er = e + (size_t)r * HPAD;
                #pragma unroll
                for (int k = 0; k < 5; ++k) er[h0 + k] = acc[j][k];
                if (hg == 13) { er[70] = 0.0f; er[71] = 0.0f; }  // zero pad cols
            }
        }
    }
}

// ---------------- K4: LSTM scan (xg fused in) ----------------
__device__ __forceinline__ float tanh_fast(float v) {
    v = fminf(fmaxf(v, -20.0f), 20.0f);
    float E = __expf(2.0f * v);
    return (E - 1.0f) / (E + 1.0f);
}
__device__ __forceinline__ float sigmoid_fast(float v) {
    return 1.0f / (1.0f + __expf(-v));
}

__global__ __launch_bounds__(320) void k_lstm(const float* __restrict__ e,
                                              const float* __restrict__ w_hh,
                                              const float* __restrict__ w_ih,
                                              const float* __restrict__ b_ih,
                                              const float* __restrict__ b_hh,
                                              float* __restrict__ hout) {
    __shared__ __align__(16) float h_lds[HPAD];
    __shared__ float gates_lds[GATES];
    const int tid = threadIdx.x;
    const int b = blockIdx.x;
    float whh[HPAD], wih[HPAD];
    float bias = 0.0f;
    if (tid < GATES) {
        bias = b_ih[tid] + b_hh[tid];
        #pragma unroll
        for (int j = 0; j < HDIM; ++j) {
            whh[j] = w_hh[tid * HDIM + j];
            wih[j] = w_ih[tid * HDIM + j];
        }
        whh[70] = whh[71] = 0.0f; wih[70] = wih[71] = 0.0f;
    } else {
        #pragma unroll
        for (int j = 0; j < HPAD; ++j) { whh[j] = 0.0f; wih[j] = 0.0f; }
    }
    if (tid < HPAD) h_lds[tid] = 0.0f;
    float c_reg = 0.0f;
    __syncthreads();

    for (int t = 0; t < TLEN; ++t) {
        const float4* erow = (const float4*)(e + ((size_t)b * TLEN + t) * HPAD);
        // x-gate part (independent of h) — 4 parallel accumulator chains
        float a0 = 0.f, a1 = 0.f, a2 = 0.f, a3 = 0.f;
        #pragma unroll
        for (int jj = 0; jj < 18; ++jj) {
            float4 ev = erow[jj];
            a0 += ev.x * wih[4 * jj];
            a1 += ev.y * wih[4 * jj + 1];
            a2 += ev.z * wih[4 * jj + 2];
            a3 += ev.w * wih[4 * jj + 3];
        }
        // recurrent part
        #pragma unroll
        for (int jj = 0; jj < 18; ++jj) {
            float4 hv = ((const float4*)h_lds)[jj];
            a0 += hv.x * whh[4 * jj];
            a1 += hv.y * whh[4 * jj + 1];
            a2 += hv.z * whh[4 * jj + 2];
            a3 += hv.w * whh[4 * jj + 3];
        }
        float acc = bias + ((a0 + a1) + (a2 + a3));
        if (tid < GATES) {
            float a;
            if (tid < 140)      a = sigmoid_fast(acc);   // i, f
            else if (tid < 210) a = tanh_fast(acc);      // g
            else                a = sigmoid_fast(acc);   // o
            gates_lds[tid] = a;
        }
        __syncthreads();
        if (tid < HDIM) {
            float iv = gates_lds[tid];
            float fv = gates_lds[tid + 70];
            float gv = gates_lds[tid + 140];
            float ov = gates_lds[tid + 210];
            c_reg = fv * c_reg + iv * gv;
            float hn = ov * tanh_fast(c_reg);
            h_lds[tid] = hn;
            hout[((size_t)b * TLEN + t) * HPAD + tid] = hn;
        }
        __syncthreads();
    }
}

// ---------------- K5a: attention energy ----------------
__global__ __launch_bounds__(256) void k_energy(const float* __restrict__ hout,
                                                const float* __restrict__ w1,
                                                const float* __restrict__ b1,
                                                const float* __restrict__ w2,
                                                const float* __restrict__ b2,
                                                float* __restrict__ energy) {
    const int lane = threadIdx.x & 63;
    const int wid = blockIdx.x * 4 + (threadIdx.x >> 6);
    float w1r[HPAD];
    #pragma unroll
    for (int c = 0; c < HDIM; ++c) w1r[c] = w1[lane * HDIM + c];
    w1r[70] = w1r[71] = 0.0f;
    const float b1v = b1[lane];
    const float w2v = w2[lane];
    const float b2v = b2[0];
    for (int row = wid; row < ROWS; row += 4096) {
        const float4* rp = (const float4*)(hout + (size_t)row * HPAD);
        float a0 = 0.f, a1 = 0.f, a2 = 0.f, a3 = 0.f;
        #pragma unroll
        for (int jj = 0; jj < 18; ++jj) {
            float4 v = rp[jj];
            a0 += v.x * w1r[4 * jj];
            a1 += v.y * w1r[4 * jj + 1];
            a2 += v.z * w1r[4 * jj + 2];
            a3 += v.w * w1r[4 * jj + 3];
        }
        float hid = fmaxf((a0 + a1) + (a2 + a3) + b1v, 0.0f) * w2v;
        #pragma unroll
        for (int off = 32; off > 0; off >>= 1) hid += __shfl_down(hid, off);
        if (lane == 0) energy[row] = hid + b2v;
    }
}

// ---------------- K5b: softmax-pool + FC + softmax ----------------
__global__ __launch_bounds__(128) void k_pool(const float* __restrict__ hout,
                                              const float* __restrict__ energy,
                                              const float* __restrict__ fc_w,
                                              const float* __restrict__ fc_b,
                                              float* __restrict__ outp) {
    __shared__ float red[128];
    __shared__ float wexp[TLEN];
    __shared__ float pooledL[HDIM];
    const int tid = threadIdx.x;
    const int b = blockIdx.x;
    float v[4];
    #pragma unroll
    for (int k = 0; k < 4; ++k) v[k] = energy[b * TLEN + tid + 128 * k];
    float m = fmaxf(fmaxf(v[0], v[1]), fmaxf(v[2], v[3]));
    red[tid] = m; __syncthreads();
    for (int s = 64; s > 0; s >>= 1) {
        if (tid < s) red[tid] = fmaxf(red[tid], red[tid + s]);
        __syncthreads();
    }
    const float M = red[0]; __syncthreads();
    float s4 = 0.f;
    #pragma unroll
    for (int k = 0; k < 4; ++k) {
        float ex = __expf(v[k] - M);
        wexp[tid + 128 * k] = ex;
        s4 += ex;
    }
    red[tid] = s4; __syncthreads();
    for (int s = 64; s > 0; s >>= 1) {
        if (tid < s) red[tid] += red[tid + s];
        __syncthreads();
    }
    const float rinv = 1.0f / red[0];
    if (tid < HDIM) {
        float a0 = 0.f, a1 = 0.f, a2 = 0.f, a3 = 0.f;
        const float* hp = hout + (size_t)b * TLEN * HPAD + tid;
        for (int s = 0; s < TLEN; s += 4) {
            a0 += wexp[s]     * hp[(size_t)(s)     * HPAD];
            a1 += wexp[s + 1] * hp[(size_t)(s + 1) * HPAD];
            a2 += wexp[s + 2] * hp[(size_t)(s + 2) * HPAD];
            a3 += wexp[s + 3] * hp[(size_t)(s + 3) * HPAD];
        }
        pooledL[tid] = ((a0 + a1) + (a2 + a3)) * rinv;
    }
    __syncthreads();
    if (tid == 0) {
        float l[3];
        #pragma unroll
        for (int i = 0; i < 3; ++i) {
            float a = fc_b[i];
            for (int h = 0; h < HDIM; ++h) a += fc_w[i * HDIM + h] * pooledL[h];
            l[i] = a;
        }
        float m3 = fmaxf(l[0], fmaxf(l[1], l[2]));
        float e0 = __expf(l[0] - m3), e1 = __expf(l[1] - m3), e2 = __expf(l[2] - m3);
        float rs = 1.0f / (e0 + e1 + e2);
        outp[b * 3 + 0] = e0 * rs;
        outp[b * 3 + 1] = e1 * rs;
        outp[b * 3 + 2] = e2 * rs;
    }
}

extern "C" void kernel_launch(void* const* d_in, const int* in_sizes, int n_in,
                              void* d_out, int out_size, void* d_ws, size_t ws_size,
                              hipStream_t stream) {
    const float* x       = (const float*)d_in[0];
    const float* embed_w = (const float*)d_in[1];
    const float* w_ih    = (const float*)d_in[2];
    const float* w_hh    = (const float*)d_in[3];
    const float* b_ih    = (const float*)d_in[4];
    const float* b_hh    = (const float*)d_in[5];
    const float* aw1     = (const float*)d_in[6];
    const float* ab1     = (const float*)d_in[7];
    const float* aw2     = (const float*)d_in[8];
    const float* ab2     = (const float*)d_in[9];
    const float* fc_w    = (const float*)d_in[10];
    const float* fc_b    = (const float*)d_in[11];
    float* outp = (float*)d_out;
    float* ws = (float*)d_ws;

    float* wrn = ws + OFF_WRN;
    float* e   = ws + OFF_E;
    float* ho  = ws + OFF_HOUT;
    float* en  = ws + OFF_ENERGY;

    k_renorm<<<1104, 64, 0, stream>>>(embed_w, wrn);
    k_embed_gemm<<<911, 256, 0, stream>>>(x, wrn, e);
    k_lstm<<<BATCH, 320, 0, stream>>>(e, w_hh, w_ih, b_ih, b_hh, ho);
    k_energy<<<1024, 256, 0, stream>>>(ho, aw1, ab1, aw2, ab2, en);
    k_pool<<<BATCH, 128, 0, stream>>>(ho, en, fc_w, fc_b, outp);
}

// Round 2
// 861.908 us; speedup vs baseline: 1.6291x; 1.6291x over previous
//
#include <hip/hip_runtime.h>
#include <math.h>

#define HDIM 70
#define HPAD 72
#define GATES 280
#define NG 288        // gates padded to 18*16
#define TLEN 512
#define BATCH 128
#define CDIM 1104
#define KW 1152       // K padded to 18*64
#define ROWS 65536    // BATCH*TLEN

// ws layout (float offsets)
#define OFF_WRN   0          // 1104*70 fp32 -> 77280 (round 77312)
#define OFF_BIAS  77312      // 280 fp32 (round 320)
#define OFF_WCT   77632      // 288*1152 bf16 = 165888 floats
#define OFF_XG    243520     // 65536*280 bf16 = 9175040 floats
#define OFF_HOUT  9418560    // 65536*72 fp32 = 4718592
#define OFF_EN    14137152   // 65536 fp32

typedef short short8 __attribute__((ext_vector_type(8)));
typedef float f32x4 __attribute__((ext_vector_type(4)));

__device__ __forceinline__ unsigned short f2bf(float f) {
    unsigned int u = __float_as_uint(f);
    u = (u + 0x7fffu + ((u >> 16) & 1u)) >> 16;
    return (unsigned short)u;
}
__device__ __forceinline__ float bf2f(unsigned short s) {
    return __uint_as_float(((unsigned int)s) << 16);
}

// ---------------- K1: row renorm of embed_w ----------------
__global__ __launch_bounds__(64) void k_renorm(const float* __restrict__ w,
                                               float* __restrict__ wrn) {
    const int row = blockIdx.x;
    const int lane = threadIdx.x;
    const float* wr = w + row * HDIM;
    float v0 = wr[lane];
    float v1 = (lane < 6) ? wr[64 + lane] : 0.0f;
    float ss = v0 * v0 + v1 * v1;
    #pragma unroll
    for (int off = 32; off > 0; off >>= 1) ss += __shfl_down(ss, off);
    float tot = __shfl(ss, 0);
    float n = sqrtf(tot);
    float scale = (n > 1.0f) ? 1.0f / (n + 1e-7f) : 1.0f;
    wrn[row * HDIM + lane] = v0 * scale;
    if (lane < 6) wrn[row * HDIM + 64 + lane] = v1 * scale;
}

// ---------------- K2: WcT[n][k] = sum_h w_ih[n][h]*wrn[k][h], bf16, padded ----------------
__global__ __launch_bounds__(256) void k_prep(const float* __restrict__ wrn,
                                              const float* __restrict__ w_ih,
                                              const float* __restrict__ b_ih,
                                              const float* __restrict__ b_hh,
                                              unsigned short* __restrict__ wcT,
                                              float* __restrict__ bias) {
    const int n = blockIdx.x;      // 0..287
    const int tid = threadIdx.x;
    float wr[HDIM];
    if (n < GATES) {
        #pragma unroll
        for (int h = 0; h < HDIM; ++h) wr[h] = w_ih[n * HDIM + h];
        if (tid == 0) bias[n] = b_ih[n] + b_hh[n];
    } else {
        #pragma unroll
        for (int h = 0; h < HDIM; ++h) wr[h] = 0.0f;
    }
    for (int c = tid; c < KW; c += 256) {
        float a = 0.0f;
        if (n < GATES && c < CDIM) {
            const float* wc = wrn + c * HDIM;
            #pragma unroll
            for (int h = 0; h < HDIM; ++h) a += wr[h] * wc[h];
        }
        wcT[(size_t)n * KW + c] = f2bf(a);
    }
}

// ---------------- K3: xg = x @ Wc + bias  (bf16 MFMA, M=65536,N=288,K=1152) ----------------
// block: 256 thr (4 waves, 2x2 wave grid), tile M=128 x N=288, K-chunks of 64.
__global__ __launch_bounds__(256, 2) void k_xg_gemm(const float* __restrict__ x,
                                                    const unsigned short* __restrict__ wcT,
                                                    const float* __restrict__ bias,
                                                    unsigned short* __restrict__ xg) {
    __shared__ __align__(16) unsigned short A_lds[128 * 72];  // [row][k] stride 72
    __shared__ __align__(16) unsigned short B_lds[NG * 72];   // [n][k]   stride 72
    const int tid = threadIdx.x;
    const int lane = tid & 63;
    const int w = tid >> 6;
    const int mh = (w >> 1) * 64;     // wave M-half: 0 or 64
    const int nh = (w & 1) * 144;     // wave N-half: 0 or 144 (9 n-tiles)
    const int l15 = lane & 15;
    const int q = lane >> 4;
    const size_t rbase = (size_t)blockIdx.x * 128;

    f32x4 acc[4][9];
    #pragma unroll
    for (int mt = 0; mt < 4; ++mt)
        #pragma unroll
        for (int nt = 0; nt < 9; ++nt) acc[mt][nt] = (f32x4){0.f, 0.f, 0.f, 0.f};

    const int r_st = tid >> 1;
    const int kh_st = (tid & 1) * 32;

    for (int kc = 0; kc < 18; ++kc) {
        const int k0 = kc * 64;
        // stage A: 128 rows x 64 k fp32 -> bf16
        {
            const float* xr = x + (rbase + r_st) * (size_t)CDIM + k0 + kh_st;
            unsigned short* dst = &A_lds[r_st * 72 + kh_st];
            #pragma unroll
            for (int qq = 0; qq < 8; ++qq) {
                const int kk = k0 + kh_st + qq * 4;
                float4 v = make_float4(0.f, 0.f, 0.f, 0.f);
                if (kk < CDIM) v = *(const float4*)(xr + qq * 4);
                unsigned int lo = (unsigned int)f2bf(v.x) | ((unsigned int)f2bf(v.y) << 16);
                unsigned int hi = (unsigned int)f2bf(v.z) | ((unsigned int)f2bf(v.w) << 16);
                uint2 pv; pv.x = lo; pv.y = hi;
                *(uint2*)&dst[qq * 4] = pv;
            }
        }
        // stage B: 288 n x 64 k bf16 (already padded with zeros)
        {
            #pragma unroll
            for (int p = 0; p < 9; ++p) {
                const int cid = tid + p * 256;
                const int n = cid >> 3;
                const int ko = (cid & 7) * 8;
                uint4 v = *(const uint4*)(wcT + (size_t)n * KW + k0 + ko);
                *(uint4*)&B_lds[n * 72 + ko] = v;
            }
        }
        __syncthreads();
        #pragma unroll
        for (int ks = 0; ks < 2; ++ks) {
            short8 a[4];
            short8 bfr[9];
            #pragma unroll
            for (int mt = 0; mt < 4; ++mt)
                a[mt] = *(const short8*)&A_lds[(mh + mt * 16 + l15) * 72 + ks * 32 + q * 8];
            #pragma unroll
            for (int nt = 0; nt < 9; ++nt)
                bfr[nt] = *(const short8*)&B_lds[(nh + nt * 16 + l15) * 72 + ks * 32 + q * 8];
            #pragma unroll
            for (int mt = 0; mt < 4; ++mt)
                #pragma unroll
                for (int nt = 0; nt < 9; ++nt)
                    acc[mt][nt] = __builtin_amdgcn_mfma_f32_16x16x32_bf16(a[mt], bfr[nt], acc[mt][nt], 0, 0, 0);
        }
        __syncthreads();
    }
    // epilogue: + bias, store bf16. D: m=(q*4+r), n=l15 within tile.
    #pragma unroll
    for (int nt = 0; nt < 9; ++nt) {
        const int n_g = nh + nt * 16 + l15;
        if (n_g >= GATES) continue;
        const float bv = bias[n_g];
        #pragma unroll
        for (int mt = 0; mt < 4; ++mt) {
            #pragma unroll
            for (int r = 0; r < 4; ++r) {
                const size_t row = rbase + mh + mt * 16 + q * 4 + r;
                xg[row * GATES + n_g] = f2bf(acc[mt][nt][r] + bv);
            }
        }
    }
}

// ---------------- K4: LSTM scan (xg precomputed, bias folded in) ----------------
__device__ __forceinline__ float tanh_fast(float v) {
    v = fminf(fmaxf(v, -20.0f), 20.0f);
    float E = __expf(2.0f * v);
    return (E - 1.0f) / (E + 1.0f);
}
__device__ __forceinline__ float sigmoid_fast(float v) {
    return 1.0f / (1.0f + __expf(-v));
}

#define PF 8
__global__ __launch_bounds__(320) void k_lstm(const unsigned short* __restrict__ xg,
                                              const float* __restrict__ w_hh,
                                              float* __restrict__ hout) {
    __shared__ __align__(16) float h_lds[HPAD];
    __shared__ float gates_lds[GATES];
    const int tid = threadIdx.x;
    const int b = blockIdx.x;
    float whh[HPAD];
    if (tid < GATES) {
        #pragma unroll
        for (int j = 0; j < HDIM; ++j) whh[j] = w_hh[tid * HDIM + j];
        whh[70] = whh[71] = 0.0f;
    } else {
        #pragma unroll
        for (int j = 0; j < HPAD; ++j) whh[j] = 0.0f;
    }
    if (tid < HPAD) h_lds[tid] = 0.0f;
    float c_reg = 0.0f;

    const unsigned short* xp = xg + (size_t)b * TLEN * GATES + (tid < GATES ? tid : 0);
    float xbuf[PF];
    #pragma unroll
    for (int i = 0; i < PF; ++i) xbuf[i] = bf2f(xp[i * GATES]);
    __syncthreads();

    #pragma unroll 8
    for (int t = 0; t < TLEN; ++t) {
        const int slot = t & (PF - 1);
        const float xcur = xbuf[slot];
        xbuf[slot] = bf2f(xp[((t + PF) & (TLEN - 1)) * GATES]);  // prefetch 8 ahead
        float a0 = 0.f, a1 = 0.f, a2 = 0.f, a3 = 0.f;
        #pragma unroll
        for (int jj = 0; jj < 18; ++jj) {
            float4 hv = ((const float4*)h_lds)[jj];
            a0 += hv.x * whh[4 * jj];
            a1 += hv.y * whh[4 * jj + 1];
            a2 += hv.z * whh[4 * jj + 2];
            a3 += hv.w * whh[4 * jj + 3];
        }
        const float acc = xcur + ((a0 + a1) + (a2 + a3));
        if (tid < GATES) {
            float a;
            if (tid < 140)      a = sigmoid_fast(acc);   // i, f
            else if (tid < 210) a = tanh_fast(acc);      // g
            else                a = sigmoid_fast(acc);   // o
            gates_lds[tid] = a;
        }
        __syncthreads();
        if (tid < HDIM) {
            const float iv = gates_lds[tid];
            const float fv = gates_lds[tid + 70];
            const float gv = gates_lds[tid + 140];
            const float ov = gates_lds[tid + 210];
            c_reg = fv * c_reg + iv * gv;
            const float hn = ov * tanh_fast(c_reg);
            h_lds[tid] = hn;
            hout[((size_t)b * TLEN + t) * HPAD + tid] = hn;
        }
        __syncthreads();
    }
}

// ---------------- K5a: attention energy ----------------
__global__ __launch_bounds__(256) void k_energy(const float* __restrict__ hout,
                                                const float* __restrict__ w1,
                                                const float* __restrict__ b1,
                                                const float* __restrict__ w2,
                                                const float* __restrict__ b2,
                                                float* __restrict__ energy) {
    const int lane = threadIdx.x & 63;
    const int wid = blockIdx.x * 4 + (threadIdx.x >> 6);
    float w1r[HPAD];
    #pragma unroll
    for (int c = 0; c < HDIM; ++c) w1r[c] = w1[lane * HDIM + c];
    w1r[70] = w1r[71] = 0.0f;
    const float b1v = b1[lane];
    const float w2v = w2[lane];
    const float b2v = b2[0];
    for (int row = wid; row < ROWS; row += 4096) {
        const float4* rp = (const float4*)(hout + (size_t)row * HPAD);
        float a0 = 0.f, a1 = 0.f, a2 = 0.f, a3 = 0.f;
        #pragma unroll
        for (int jj = 0; jj < 18; ++jj) {
            float4 v = rp[jj];
            a0 += v.x * w1r[4 * jj];
            a1 += v.y * w1r[4 * jj + 1];
            a2 += v.z * w1r[4 * jj + 2];
            a3 += v.w * w1r[4 * jj + 3];
        }
        float hid = fmaxf((a0 + a1) + (a2 + a3) + b1v, 0.0f) * w2v;
        #pragma unroll
        for (int off = 32; off > 0; off >>= 1) hid += __shfl_down(hid, off);
        if (lane == 0) energy[row] = hid + b2v;
    }
}

// ---------------- K5b: softmax-pool + FC + softmax ----------------
__global__ __launch_bounds__(128) void k_pool(const float* __restrict__ hout,
                                              const float* __restrict__ energy,
                                              const float* __restrict__ fc_w,
                                              const float* __restrict__ fc_b,
                                              float* __restrict__ outp) {
    __shared__ float red[128];
    __shared__ float wexp[TLEN];
    __shared__ float pooledL[HDIM];
    const int tid = threadIdx.x;
    const int b = blockIdx.x;
    float v[4];
    #pragma unroll
    for (int k = 0; k < 4; ++k) v[k] = energy[b * TLEN + tid + 128 * k];
    float m = fmaxf(fmaxf(v[0], v[1]), fmaxf(v[2], v[3]));
    red[tid] = m; __syncthreads();
    for (int s = 64; s > 0; s >>= 1) {
        if (tid < s) red[tid] = fmaxf(red[tid], red[tid + s]);
        __syncthreads();
    }
    const float M = red[0]; __syncthreads();
    float s4 = 0.f;
    #pragma unroll
    for (int k = 0; k < 4; ++k) {
        float ex = __expf(v[k] - M);
        wexp[tid + 128 * k] = ex;
        s4 += ex;
    }
    red[tid] = s4; __syncthreads();
    for (int s = 64; s > 0; s >>= 1) {
        if (tid < s) red[tid] += red[tid + s];
        __syncthreads();
    }
    const float rinv = 1.0f / red[0];
    if (tid < HDIM) {
        float a0 = 0.f, a1 = 0.f, a2 = 0.f, a3 = 0.f;
        const float* hp = hout + (size_t)b * TLEN * HPAD + tid;
        for (int s = 0; s < TLEN; s += 4) {
            a0 += wexp[s]     * hp[(size_t)(s)     * HPAD];
            a1 += wexp[s + 1] * hp[(size_t)(s + 1) * HPAD];
            a2 += wexp[s + 2] * hp[(size_t)(s + 2) * HPAD];
            a3 += wexp[s + 3] * hp[(size_t)(s + 3) * HPAD];
        }
        pooledL[tid] = ((a0 + a1) + (a2 + a3)) * rinv;
    }
    __syncthreads();
    if (tid == 0) {
        float l[3];
        #pragma unroll
        for (int i = 0; i < 3; ++i) {
            float a = fc_b[i];
            for (int h = 0; h < HDIM; ++h) a += fc_w[i * HDIM + h] * pooledL[h];
            l[i] = a;
        }
        float m3 = fmaxf(l[0], fmaxf(l[1], l[2]));
        float e0 = __expf(l[0] - m3), e1 = __expf(l[1] - m3), e2 = __expf(l[2] - m3);
        float rs = 1.0f / (e0 + e1 + e2);
        outp[b * 3 + 0] = e0 * rs;
        outp[b * 3 + 1] = e1 * rs;
        outp[b * 3 + 2] = e2 * rs;
    }
}

extern "C" void kernel_launch(void* const* d_in, const int* in_sizes, int n_in,
                              void* d_out, int out_size, void* d_ws, size_t ws_size,
                              hipStream_t stream) {
    const float* x       = (const float*)d_in[0];
    const float* embed_w = (const float*)d_in[1];
    const float* w_ih    = (const float*)d_in[2];
    const float* w_hh    = (const float*)d_in[3];
    const float* b_ih    = (const float*)d_in[4];
    const float* b_hh    = (const float*)d_in[5];
    const float* aw1     = (const float*)d_in[6];
    const float* ab1     = (const float*)d_in[7];
    const float* aw2     = (const float*)d_in[8];
    const float* ab2     = (const float*)d_in[9];
    const float* fc_w    = (const float*)d_in[10];
    const float* fc_b    = (const float*)d_in[11];
    float* outp = (float*)d_out;
    float* ws = (float*)d_ws;

    float* wrn  = ws + OFF_WRN;
    float* bias = ws + OFF_BIAS;
    unsigned short* wcT = (unsigned short*)(ws + OFF_WCT);
    unsigned short* xgp = (unsigned short*)(ws + OFF_XG);
    float* ho = ws + OFF_HOUT;
    float* en = ws + OFF_EN;

    k_renorm<<<CDIM, 64, 0, stream>>>(embed_w, wrn);
    k_prep<<<NG, 256, 0, stream>>>(wrn, w_ih, b_ih, b_hh, wcT, bias);
    k_xg_gemm<<<512, 256, 0, stream>>>(x, wcT, bias, xgp);
    k_lstm<<<BATCH, 320, 0, stream>>>(xgp, w_hh, ho);
    k_energy<<<1024, 256, 0, stream>>>(ho, aw1, ab1, aw2, ab2, en);
    k_pool<<<BATCH, 128, 0, stream>>>(ho, en, fc_w, fc_b, outp);
}